// Round 11
// baseline (5078.527 us; speedup 1.0000x reference)
//
#include <hip/hip_runtime.h>

#define B_ 8
#define T_ 256
#define U_ 101
#define V_ 512
#define UM1 (U_ - 1)
#define DSTR 128    // floats per diagonal row (u-index stride)
#define DALLOC 488  // diagonals allocated (prefetch reads up to 448)
#define CH 32       // DP stages per LDS chunk
#define NCH 12      // chunks computed (12*32 = 384 >= 355 needed)
#define NEG -1e30f
#define LOG2E 1.4426950408889634f
#define LN2 0.6931471805599453f

typedef float floatx4 __attribute__((ext_vector_type(4)));
typedef float floatx2 __attribute__((ext_vector_type(2)));

__device__ __forceinline__ float lae2(float a, float b) {
  float m = fmaxf(a, b);
  float d = fminf(a, b) - m;
  return m + __builtin_log2f(1.0f + __builtin_exp2f(d));
}

// lane n <- lane n-1 (DPP wave_shr:1, VALU latency). Lane 0 <- NEG.
__device__ __forceinline__ float wave_shr1_neg(float x) {
  int r = __builtin_amdgcn_update_dpp(__float_as_int(NEG), __float_as_int(x),
                                      0x138, 0xF, 0xF, false);
  return __int_as_float(r);
}

__device__ __forceinline__ float clamp01n(float x) {
  return fminf(fmaxf(x, -1.0f), 0.0f);  // also kills NaN/-inf
}

// ---------------- lse (unchanged from R10) ----------------
__global__ __launch_bounds__(256) void lse_kernel(
    const float* __restrict__ acts, const int* __restrict__ labels,
    const int* __restrict__ act_lens, const int* __restrict__ label_lens,
    float* __restrict__ blankD, float* __restrict__ emitD,
    float* __restrict__ bp2) {
  const int wv = blockIdx.x * 4 + (threadIdx.x >> 6);
  const int lane = threadIdx.x & 63;
  const int r0 = wv * 2;  // row = (b*T + t)*U + u
  const int r1 = r0 + 1;
  const floatx4* p0 = (const floatx4*)(acts + (size_t)r0 * V_);
  const floatx4* p1 = (const floatx4*)(acts + (size_t)r1 * V_);
  floatx4 a0 = p0[lane];
  floatx4 a1 = p0[lane + 64];
  floatx4 c0 = p1[lane];
  floatx4 c1 = p1[lane + 64];
  float s0 = __builtin_exp2f(a0.x * LOG2E) + __builtin_exp2f(a0.y * LOG2E) +
             __builtin_exp2f(a0.z * LOG2E) + __builtin_exp2f(a0.w * LOG2E) +
             __builtin_exp2f(a1.x * LOG2E) + __builtin_exp2f(a1.y * LOG2E) +
             __builtin_exp2f(a1.z * LOG2E) + __builtin_exp2f(a1.w * LOG2E);
  float s1 = __builtin_exp2f(c0.x * LOG2E) + __builtin_exp2f(c0.y * LOG2E) +
             __builtin_exp2f(c0.z * LOG2E) + __builtin_exp2f(c0.w * LOG2E) +
             __builtin_exp2f(c1.x * LOG2E) + __builtin_exp2f(c1.y * LOG2E) +
             __builtin_exp2f(c1.z * LOG2E) + __builtin_exp2f(c1.w * LOG2E);
#pragma unroll
  for (int s = 32; s >= 1; s >>= 1) {
    s0 += __shfl_xor(s0, s);
    s1 += __shfl_xor(s1, s);
  }
  const float d0 = __builtin_log2f(s0);
  const float d1 = __builtin_log2f(s1);

#define EMIT_ROW(r, v0, v1, denom2)                                           \
  {                                                                           \
    const int u = (r) % U_;                                                   \
    const int bt = (r) / U_;                                                  \
    const int t = bt % T_;                                                    \
    const int b = bt / T_;                                                    \
    float emitv = 0.0f;                                                       \
    if (u < UM1) {                                                            \
      int e = labels[b * UM1 + u]; /* in [1, V) */                            \
      floatx4 sel = (e < 256) ? v0 : v1;                                      \
      int k = e & 3;                                                          \
      float cand =                                                            \
          (k == 0) ? sel.x : (k == 1) ? sel.y : (k == 2) ? sel.z : sel.w;     \
      emitv = __shfl(cand, (e & 255) >> 2);                                   \
    }                                                                         \
    if (lane == 0) {                                                          \
      const float blank2 = v0.x * LOG2E - (denom2);                           \
      blankD[((size_t)b * DALLOC + (t + u + 1)) * DSTR + u] = blank2;         \
      if (t == 0) blankD[((size_t)b * DALLOC + u) * DSTR + u] = NEG;          \
      if (u < UM1)                                                            \
        emitD[((size_t)b * DALLOC + (t + u + 1)) * DSTR + (u + 1)] =          \
            emitv * LOG2E - (denom2);                                         \
      if (t == act_lens[b] - 1 && u == label_lens[b]) bp2[b] = blank2;        \
    }                                                                         \
  }

  EMIT_ROW(r0, a0, a1, d0)
  EMIT_ROW(r1, c0, c1, d1)
#undef EMIT_ROW
}

// ---------------- dp (unchanged from R10) ----------------
__global__ __launch_bounds__(64, 1) void dp_kernel(
    const float* __restrict__ blankD, const float* __restrict__ emitD,
    const float* __restrict__ bp2, const int* __restrict__ act_lens,
    const int* __restrict__ label_lens, float* __restrict__ out) {
  __shared__ float lds[2][2][CH][DSTR];
  const int b = blockIdx.x;
  const int lane = threadIdx.x;
  const int tl1 = act_lens[b] - 1;
  const int ulen = label_lens[b];
  const int dtar = tl1 + ulen;
  const int uE = 2 * lane;
  const int uO = 2 * lane + 1;
  const bool capE = ((ulen & 1) == 0) && (lane == (ulen >> 1));
  const bool capO = ((ulen & 1) == 1) && (lane == (ulen >> 1));
  const floatx4* g4B = (const floatx4*)(blankD + (size_t)b * DALLOC * DSTR);
  const floatx4* g4E = (const floatx4*)(emitD + (size_t)b * DALLOC * DSTR);

  floatx4 rB[16], rE[16];
#pragma unroll
  for (int j = 0; j < 16; ++j) {
    rB[j] = g4B[32 + j * 64 + lane];
    rE[j] = g4E[32 + j * 64 + lane];
  }
  {
    floatx4* lB4 = (floatx4*)&lds[0][0][0][0];
    floatx4* lE4 = (floatx4*)&lds[0][1][0][0];
#pragma unroll
    for (int j = 0; j < 16; ++j) {
      lB4[j * 64 + lane] = rB[j];
      lE4[j * 64 + lane] = rE[j];
    }
  }
  float xE = (lane == 0) ? 0.0f : NEG;
  float xO = NEG;
  float res = NEG;

  for (int c = 0; c < NCH; ++c) {
    const int buf = c & 1;
    const int nb = ((c + 1) * CH + 1) * 32;
#pragma unroll
    for (int j = 0; j < 16; ++j) {
      rB[j] = g4B[(size_t)nb + j * 64 + lane];
      rE[j] = g4E[(size_t)nb + j * 64 + lane];
    }
    const floatx2* lB2 = (const floatx2*)&lds[buf][0][0][0];
    const floatx2* lE2 = (const floatx2*)&lds[buf][1][0][0];
    floatx2 pB[4], pE[4];
#pragma unroll
    for (int k = 0; k < 4; ++k) {
      pB[k] = lB2[k * 64 + lane];
      pE[k] = lE2[k * 64 + lane];
    }
    const int dbase = c * CH + 1;
#pragma unroll
    for (int k = 0; k < CH; ++k) {
      const int d = dbase + k;
      const floatx2 Bv = pB[k & 3];
      const floatx2 Ev = pE[k & 3];
      if (k + 4 < CH) {
        pB[k & 3] = lB2[(k + 4) * 64 + lane];
        pE[k & 3] = lE2[(k + 4) * 64 + lane];
      }
      const float xm1E = wave_shr1_neg(xO);
      const float vtE = xE + Bv.x;
      const float htE = xm1E + Ev.x;
      const float vtO = xO + Bv.y;
      const float htO = xE + Ev.y;
      const float nxE = lae2(vtE, htE);
      const float nxO = lae2(vtO, htO);
      const bool vE = (d >= uE) && (d - uE <= tl1) && (uE <= UM1);
      const bool vO = (d >= uO) && (d - uO <= tl1) && (uO <= UM1);
      xE = vE ? nxE : xE;
      xO = vO ? nxO : xO;
      if (d == dtar) res = capE ? xE : (capO ? xO : res);
    }
    floatx4* wB4 = (floatx4*)&lds[buf ^ 1][0][0][0];
    floatx4* wE4 = (floatx4*)&lds[buf ^ 1][1][0][0];
#pragma unroll
    for (int j = 0; j < 16; ++j) {
      wB4[j * 64 + lane] = rB[j];
      wE4[j * 64 + lane] = rE[j];
    }
  }
  if (capE || capO) out[b] = -((res + bp2[b]) * LN2);
}

// ---------------- PROBES (this round only; outputs go to ws scratch) -------

// P0: 393,216 dependent v_add_f32 -> effective clock (4 cy/add dep latency).
__global__ __launch_bounds__(64, 1) void probe_add(const float* __restrict__ init,
                                                   float* __restrict__ o) {
  const int lane = threadIdx.x;
  float x = clamp01n(init[lane]);
  const float y = clamp01n(init[lane + 64]) - 1.0f;  // in [-2,-1]
#pragma unroll 1
  for (int k = 0; k < 49152; ++k) {
    x += y; x += y; x += y; x += y; x += y; x += y; x += y; x += y;
  }
  o[lane] = x;
}

// P1: 24,576 stages of the exact dp arithmetic, register inputs only.
__global__ __launch_bounds__(64, 1) void probe_chain(
    const float* __restrict__ init, float* __restrict__ o) {
  const int lane = threadIdx.x;
  float xE = clamp01n(init[lane]);
  float xO = clamp01n(init[lane + 64]);
  const float Bx = clamp01n(init[lane + 128]);
  const float By = clamp01n(init[lane + 192]);
  const float Ex = clamp01n(init[lane + 256]);
  const float Ey = clamp01n(init[lane + 320]);
#pragma unroll 1
  for (int k = 0; k < 24576; ++k) {
    const float xm1E = wave_shr1_neg(xO);
    const float vtE = xE + Bx;
    const float htE = xm1E + Ex;
    const float vtO = xO + By;
    const float htO = xE + Ey;
    const float nxE = lae2(vtE, htE);
    const float nxO = lae2(vtO, htO);
    xE = (k & 1) ? nxE : xE;
    xO = nxO;
  }
  o[lane] = xE + xO;
}

// P2: 10,240 stages with the dp's ds_read prefetch structure, no global VMEM.
__global__ __launch_bounds__(64, 1) void probe_lds(const float* __restrict__ gB,
                                                   float* __restrict__ o) {
  __shared__ float lds[2][CH][DSTR];  // 32 KB
  const int lane = threadIdx.x;
  const floatx4* g4 = (const floatx4*)gB;
#pragma unroll 1
  for (int j = 0; j < 16; ++j) {
    ((floatx4*)&lds[0][0][0])[j * 64 + lane] = g4[j * 64 + lane];
    ((floatx4*)&lds[1][0][0])[j * 64 + lane] = g4[1024 + j * 64 + lane];
  }
  float xE = 0.0f, xO = NEG;
#pragma unroll 1
  for (int c = 0; c < 320; ++c) {
    const floatx2* lB2 = (const floatx2*)&lds[c & 1][0][0];
    const floatx2* lE2 = (const floatx2*)&lds[(c & 1) ^ 1][0][0];
    floatx2 pB[4], pE[4];
#pragma unroll
    for (int k = 0; k < 4; ++k) {
      pB[k] = lB2[k * 64 + lane];
      pE[k] = lE2[k * 64 + lane];
    }
#pragma unroll
    for (int k = 0; k < CH; ++k) {
      const floatx2 Bv = pB[k & 3];
      const floatx2 Ev = pE[k & 3];
      if (k + 4 < CH) {
        pB[k & 3] = lB2[(k + 4) * 64 + lane];
        pE[k & 3] = lE2[(k + 4) * 64 + lane];
      }
      const float xm1E = wave_shr1_neg(xO);
      const float vtE = xE + Bv.x;
      const float htE = xm1E + Ev.x;
      const float vtO = xO + Bv.y;
      const float htO = xE + Ev.y;
      const float nxE = lae2(vtE, htE);
      const float nxO = lae2(vtO, htO);
      xE = ((k + c) & 1) ? nxE : xE;
      xO = nxO;
    }
  }
  o[lane] = xE + xO;
}

// P3: full dp structure (global staging + LDS + chain) looped x10.
__global__ __launch_bounds__(64, 1) void probe_full(
    const float* __restrict__ blankD, const float* __restrict__ emitD,
    float* __restrict__ o) {
  __shared__ float lds[2][2][CH][DSTR];
  const int b = blockIdx.x;
  const int lane = threadIdx.x;
  const floatx4* g4B = (const floatx4*)(blankD + (size_t)b * DALLOC * DSTR);
  const floatx4* g4E = (const floatx4*)(emitD + (size_t)b * DALLOC * DSTR);
  floatx4 rB[16], rE[16];
#pragma unroll
  for (int j = 0; j < 16; ++j) {
    rB[j] = g4B[32 + j * 64 + lane];
    rE[j] = g4E[32 + j * 64 + lane];
  }
  {
    floatx4* lB4 = (floatx4*)&lds[0][0][0][0];
    floatx4* lE4 = (floatx4*)&lds[0][1][0][0];
#pragma unroll
    for (int j = 0; j < 16; ++j) {
      lB4[j * 64 + lane] = rB[j];
      lE4[j * 64 + lane] = rE[j];
    }
  }
  float xE = 0.0f, xO = NEG;
#pragma unroll 1
  for (int c = 0; c < NCH * 10; ++c) {
    const int cm = c % NCH;
    const int buf = c & 1;
    const int nb = ((cm + 1) * CH + 1) * 32;
#pragma unroll
    for (int j = 0; j < 16; ++j) {
      rB[j] = g4B[(size_t)nb + j * 64 + lane];
      rE[j] = g4E[(size_t)nb + j * 64 + lane];
    }
    const floatx2* lB2 = (const floatx2*)&lds[buf][0][0][0];
    const floatx2* lE2 = (const floatx2*)&lds[buf][1][0][0];
    floatx2 pB[4], pE[4];
#pragma unroll
    for (int k = 0; k < 4; ++k) {
      pB[k] = lB2[k * 64 + lane];
      pE[k] = lE2[k * 64 + lane];
    }
#pragma unroll
    for (int k = 0; k < CH; ++k) {
      const floatx2 Bv = pB[k & 3];
      const floatx2 Ev = pE[k & 3];
      if (k + 4 < CH) {
        pB[k & 3] = lB2[(k + 4) * 64 + lane];
        pE[k & 3] = lE2[(k + 4) * 64 + lane];
      }
      const float xm1E = wave_shr1_neg(xO);
      const float vtE = xE + Bv.x;
      const float htE = xm1E + Ev.x;
      const float vtO = xO + Bv.y;
      const float htO = xE + Ev.y;
      const float nxE = lae2(vtE, htE);
      const float nxO = lae2(vtO, htO);
      xE = ((k + c) & 1) ? nxE : xE;
      xO = nxO;
    }
    floatx4* wB4 = (floatx4*)&lds[buf ^ 1][0][0][0];
    floatx4* wE4 = (floatx4*)&lds[buf ^ 1][1][0][0];
#pragma unroll
    for (int j = 0; j < 16; ++j) {
      wB4[j * 64 + lane] = rB[j];
      wE4[j * 64 + lane] = rE[j];
    }
  }
  o[(size_t)b * 64 + lane] = xE + xO;
}

extern "C" void kernel_launch(void* const* d_in, const int* in_sizes, int n_in,
                              void* d_out, int out_size, void* d_ws, size_t ws_size,
                              hipStream_t stream) {
  const float* acts = (const float*)d_in[0];
  const int* labels = (const int*)d_in[1];
  const int* act_lens = (const int*)d_in[2];
  const int* label_lens = (const int*)d_in[3];
  float* out = (float*)d_out;
  float* blankD = (float*)d_ws;                         // B*DALLOC*DSTR floats
  float* emitD = blankD + (size_t)B_ * DALLOC * DSTR;   // B*DALLOC*DSTR floats
  float* bp2 = emitD + (size_t)B_ * DALLOC * DSTR;      // B floats
  float* scratch = bp2 + 64;                            // probe outputs
  const int nwaves2 = B_ * T_ * U_ / 2;
  lse_kernel<<<nwaves2 / 4, 256, 0, stream>>>(acts, labels, act_lens,
                                              label_lens, blankD, emitD, bp2);
  // --- measurement probes (read post-lse blankD as benign init data) ---
  probe_add<<<1, 64, 0, stream>>>(blankD, scratch);
  probe_chain<<<1, 64, 0, stream>>>(blankD, scratch + 64);
  probe_lds<<<1, 64, 0, stream>>>(blankD, scratch + 128);
  probe_full<<<8, 64, 0, stream>>>(blankD, emitD, scratch + 192);
  // --- real dp ---
  dp_kernel<<<B_, 64, 0, stream>>>(blankD, emitD, bp2, act_lens, label_lens,
                                   out);
}

// Round 12
// 103.562 us; speedup vs baseline: 49.0386x; 49.0386x over previous
//
#include <hip/hip_runtime.h>

#define B_ 8
#define T_ 256
#define U_ 101
#define V_ 512
#define UM1 (U_ - 1)
#define DSTR 128    // floats per diagonal row (u-index stride)
#define DALLOC 488  // diagonals allocated (prefetch reads up to ~417)
#define CH 32       // DP stages per LDS chunk
#define NCH 12      // chunks computed (12*32 = 384 >= 355 needed)
#define CS 512.0f   // 2^9 per-step growth factor baked into staged probs
#define LOG2E 1.4426950408889634f
#define LN2 0.6931471805599453f

typedef float floatx4 __attribute__((ext_vector_type(4)));
typedef float floatx2 __attribute__((ext_vector_type(2)));

// lane n <- lane n-1 (DPP wave_shr:1, VALU latency). Lane 0 <- 0.0f
// (additive identity in the linear-domain DP).
__device__ __forceinline__ float wave_shr1_zero(float x) {
  int r = __builtin_amdgcn_update_dpp(0, __float_as_int(x), 0x138, 0xF, 0xF,
                                      false);
  return __int_as_float(r);
}

// Two rows of V=512 logits per wave (4 KB contiguous), wave index linear in
// acts memory order. Max-free softmax denominator. Stores LINEAR-domain
// scaled transition probs, diagonal-major, for the DP kernel:
//   Bs[t,u] = e^logit_blank / sum * 2^9  -> blankD[b][t+u+1][u]
//   Es[t,u] = e^logit_label / sum * 2^9  -> emitD [b][t+u+1][u+1]
// Unwritten slots are pre-zeroed (memset) = additive identity.
// Also writes bp2[b] = log2 P(blank | tlen-1, ulen) for the final loss term.
__global__ __launch_bounds__(256) void lse_kernel(
    const float* __restrict__ acts, const int* __restrict__ labels,
    const int* __restrict__ act_lens, const int* __restrict__ label_lens,
    float* __restrict__ blankD, float* __restrict__ emitD,
    float* __restrict__ bp2) {
  const int wv = blockIdx.x * 4 + (threadIdx.x >> 6);
  const int lane = threadIdx.x & 63;
  const int r0 = wv * 2;  // row = (b*T + t)*U + u
  const int r1 = r0 + 1;
  const floatx4* p0 = (const floatx4*)(acts + (size_t)r0 * V_);
  const floatx4* p1 = (const floatx4*)(acts + (size_t)r1 * V_);
  floatx4 a0 = p0[lane];
  floatx4 a1 = p0[lane + 64];
  floatx4 c0 = p1[lane];
  floatx4 c1 = p1[lane + 64];
  float s0 = __builtin_exp2f(a0.x * LOG2E) + __builtin_exp2f(a0.y * LOG2E) +
             __builtin_exp2f(a0.z * LOG2E) + __builtin_exp2f(a0.w * LOG2E) +
             __builtin_exp2f(a1.x * LOG2E) + __builtin_exp2f(a1.y * LOG2E) +
             __builtin_exp2f(a1.z * LOG2E) + __builtin_exp2f(a1.w * LOG2E);
  float s1 = __builtin_exp2f(c0.x * LOG2E) + __builtin_exp2f(c0.y * LOG2E) +
             __builtin_exp2f(c0.z * LOG2E) + __builtin_exp2f(c0.w * LOG2E) +
             __builtin_exp2f(c1.x * LOG2E) + __builtin_exp2f(c1.y * LOG2E) +
             __builtin_exp2f(c1.z * LOG2E) + __builtin_exp2f(c1.w * LOG2E);
#pragma unroll
  for (int s = 32; s >= 1; s >>= 1) {
    s0 += __shfl_xor(s0, s);
    s1 += __shfl_xor(s1, s);
  }

#define EMIT_ROW(r, v0, v1, ssum)                                             \
  {                                                                           \
    const int u = (r) % U_;                                                   \
    const int bt = (r) / U_;                                                  \
    const int t = bt % T_;                                                    \
    const int b = bt / T_;                                                    \
    float emitv = 0.0f;                                                       \
    if (u < UM1) {                                                            \
      int e = labels[b * UM1 + u]; /* in [1, V) */                            \
      floatx4 sel = (e < 256) ? v0 : v1;                                      \
      int k = e & 3;                                                          \
      float cand =                                                            \
          (k == 0) ? sel.x : (k == 1) ? sel.y : (k == 2) ? sel.z : sel.w;     \
      emitv = __shfl(cand, (e & 255) >> 2);                                   \
    }                                                                         \
    if (lane == 0) {                                                          \
      const float rs = CS * __builtin_amdgcn_rcpf(ssum);                      \
      blankD[((size_t)b * DALLOC + (t + u + 1)) * DSTR + u] =                 \
          __builtin_exp2f(v0.x * LOG2E) * rs;                                 \
      if (u < UM1)                                                            \
        emitD[((size_t)b * DALLOC + (t + u + 1)) * DSTR + (u + 1)] =          \
            __builtin_exp2f(emitv * LOG2E) * rs;                              \
      if (t == act_lens[b] - 1 && u == label_lens[b])                         \
        bp2[b] = v0.x * LOG2E - __builtin_log2f(ssum);                        \
    }                                                                         \
  }

  EMIT_ROW(r0, a0, a1, s0)
  EMIT_ROW(r1, c0, c1, s1)
#undef EMIT_ROW
}

// One wave per example. Anti-diagonal wavefront in the LINEAR domain; lane l
// owns columns u=2l, 2l+1. Per-stage serial chain: ONE FMA (no transcendental
// ops). Staged values carry a 2^9/step growth factor; a power-of-2 renorm per
// 32-stage chunk (tracked in S) keeps everything in fp32 range. Zero-staged
// out-of-lattice slots make boundary masks unnecessary. Chunks of 32
// diagonals staged global->regs->LDS (double-buffered); stage loop reads LDS
// only, 8-deep register prefetch.
__global__ __launch_bounds__(64, 1) void dp_kernel(
    const float* __restrict__ blankD, const float* __restrict__ emitD,
    const float* __restrict__ bp2, const int* __restrict__ act_lens,
    const int* __restrict__ label_lens, float* __restrict__ out) {
  __shared__ float lds[2][2][CH][DSTR];  // 128 KB
  const int b = blockIdx.x;
  const int lane = threadIdx.x;
  const int tl1 = act_lens[b] - 1;
  const int ulen = label_lens[b];
  const int dtar = tl1 + ulen;
  const bool capE = ((ulen & 1) == 0) && (lane == (ulen >> 1));
  const bool capO = ((ulen & 1) == 1) && (lane == (ulen >> 1));
  const floatx4* g4B = (const floatx4*)(blankD + (size_t)b * DALLOC * DSTR);
  const floatx4* g4E = (const floatx4*)(emitD + (size_t)b * DALLOC * DSTR);

  floatx4 rB[16], rE[16];
#pragma unroll
  for (int j = 0; j < 16; ++j) {
    rB[j] = g4B[32 + j * 64 + lane];  // chunk 0 = diagonals 1..32
    rE[j] = g4E[32 + j * 64 + lane];
  }
  {
    floatx4* lB4 = (floatx4*)&lds[0][0][0][0];
    floatx4* lE4 = (floatx4*)&lds[0][1][0][0];
#pragma unroll
    for (int j = 0; j < 16; ++j) {
      lB4[j * 64 + lane] = rB[j];
      lE4[j * 64 + lane] = rE[j];
    }
  }
  float xE = (lane == 0) ? 1.0f : 0.0f;  // A[0,0] = 1 at diagonal 0
  float xO = 0.0f;
  float res = 0.0f, capS = 0.0f, S = 0.0f;

  for (int c = 0; c < NCH; ++c) {
    const int buf = c & 1;
    const int nb = ((c + 1) * CH + 1) * 32;  // next chunk, x4 units
#pragma unroll
    for (int j = 0; j < 16; ++j) {
      rB[j] = g4B[(size_t)nb + j * 64 + lane];
      rE[j] = g4E[(size_t)nb + j * 64 + lane];
    }
    const floatx2* lB2 = (const floatx2*)&lds[buf][0][0][0];
    const floatx2* lE2 = (const floatx2*)&lds[buf][1][0][0];
    floatx2 pB[8], pE[8];
#pragma unroll
    for (int k = 0; k < 8; ++k) {
      pB[k] = lB2[k * 64 + lane];
      pE[k] = lE2[k * 64 + lane];
    }
    const int dbase = c * CH + 1;
#pragma unroll
    for (int k = 0; k < CH; ++k) {
      const int d = dbase + k;
      const floatx2 Bv = pB[k & 7];
      const floatx2 Ev = pE[k & 7];
      if (k + 8 < CH) {
        pB[k & 7] = lB2[(k + 8) * 64 + lane];
        pE[k & 7] = lE2[(k + 8) * 64 + lane];
      }
      const float xm1E = wave_shr1_zero(xO);  // col uE-1, prev diagonal
      const float nxE = __builtin_fmaf(xE, Bv.x, xm1E * Ev.x);
      const float nxO = __builtin_fmaf(xO, Bv.y, xE * Ev.y);
      if (d == dtar) {
        res = capE ? nxE : (capO ? nxO : res);
        capS = S;
      }
      xE = nxE;
      xO = nxO;
    }
    // Power-of-2 renorm (once per chunk; post-capture-safe since capS saved).
    float m = fmaxf(xE, xO);
#pragma unroll
    for (int s = 32; s >= 1; s >>= 1) m = fmaxf(m, __shfl_xor(m, s));
    if (m > 0.0f) {
      const float ex = floorf(__builtin_log2f(m));
      const float sc = __builtin_exp2f(-ex);
      xE *= sc;
      xO *= sc;
      S += ex;
    }
    // Write staged next chunk into the other buffer.
    floatx4* wB4 = (floatx4*)&lds[buf ^ 1][0][0][0];
    floatx4* wE4 = (floatx4*)&lds[buf ^ 1][1][0][0];
#pragma unroll
    for (int j = 0; j < 16; ++j) {
      wB4[j * 64 + lane] = rB[j];
      wE4[j * 64 + lane] = rE[j];
    }
  }
  // log2(alpha[tlen-1,ulen]) = log2(res) + capS - 9*dtar  (undo 2^9/step)
  if (capE || capO)
    out[b] = -((__builtin_log2f(res) + capS - 9.0f * (float)dtar + bp2[b]) *
               LN2);
}

extern "C" void kernel_launch(void* const* d_in, const int* in_sizes, int n_in,
                              void* d_out, int out_size, void* d_ws, size_t ws_size,
                              hipStream_t stream) {
  const float* acts = (const float*)d_in[0];
  const int* labels = (const int*)d_in[1];
  const int* act_lens = (const int*)d_in[2];
  const int* label_lens = (const int*)d_in[3];
  float* out = (float*)d_out;
  float* blankD = (float*)d_ws;                         // B*DALLOC*DSTR floats
  float* emitD = blankD + (size_t)B_ * DALLOC * DSTR;   // B*DALLOC*DSTR floats
  float* bp2 = emitD + (size_t)B_ * DALLOC * DSTR;      // B floats
  // Zero both staging arrays: unwritten slots must be the additive identity.
  hipMemsetAsync(blankD, 0, (size_t)2 * B_ * DALLOC * DSTR * sizeof(float),
                 stream);
  const int nwaves2 = B_ * T_ * U_ / 2;
  lse_kernel<<<nwaves2 / 4, 256, 0, stream>>>(acts, labels, act_lens,
                                              label_lens, blankD, emitD, bp2);
  dp_kernel<<<B_, 64, 0, stream>>>(blankD, emitD, bp2, act_lens, label_lens,
                                   out);
}

// Round 13
// 95.572 us; speedup vs baseline: 53.1382x; 1.0836x over previous
//
#include <hip/hip_runtime.h>

#define B_ 8
#define T_ 256
#define U_ 101
#define V_ 512
#define UM1 (U_ - 1)
#define DSTR 128    // floats per diagonal row (u-index stride)
#define DALLOC 488  // diagonals allocated
#define CH 32       // DP stages per LDS chunk
#define NCHD 6      // chunks per direction (6*32 = 192 >= ceil(355/2)+1)
#define CS 512.0f   // 2^9 per-step growth factor baked into staged probs
#define LOG2E 1.4426950408889634f
#define LN2 0.6931471805599453f

typedef float floatx4 __attribute__((ext_vector_type(4)));
typedef float floatx2 __attribute__((ext_vector_type(2)));

// lane n <- lane n-1 (DPP wave_shr:1). Lane 0 <- 0 (additive identity).
__device__ __forceinline__ float wave_shr1_zero(float x) {
  int r = __builtin_amdgcn_update_dpp(0, __float_as_int(x), 0x138, 0xF, 0xF,
                                      false);
  return __int_as_float(r);
}
// lane n <- lane n+1 (DPP wave_shl:1). Lane 63 <- 0.
__device__ __forceinline__ float wave_shl1_zero(float x) {
  int r = __builtin_amdgcn_update_dpp(0, __float_as_int(x), 0x130, 0xF, 0xF,
                                      false);
  return __int_as_float(r);
}

// Two rows of V=512 logits per wave, linear in acts memory order. Max-free
// softmax denominator; stores LINEAR-domain scaled probs diagonal-major:
//   blankD[b][t+u+1][u]   = e^blank_logit / sum * 2^9
//   emitD [b][t+u+1][u+1] = e^label_logit / sum * 2^9
// Unwritten slots are pre-zeroed (memset) = additive identity.
__global__ __launch_bounds__(256) void lse_kernel(
    const float* __restrict__ acts, const int* __restrict__ labels,
    float* __restrict__ blankD, float* __restrict__ emitD) {
  const int wv = blockIdx.x * 4 + (threadIdx.x >> 6);
  const int lane = threadIdx.x & 63;
  const int r0 = wv * 2;  // row = (b*T + t)*U + u
  const int r1 = r0 + 1;
  const floatx4* p0 = (const floatx4*)(acts + (size_t)r0 * V_);
  const floatx4* p1 = (const floatx4*)(acts + (size_t)r1 * V_);
  floatx4 a0 = p0[lane];
  floatx4 a1 = p0[lane + 64];
  floatx4 c0 = p1[lane];
  floatx4 c1 = p1[lane + 64];
  float s0 = __builtin_exp2f(a0.x * LOG2E) + __builtin_exp2f(a0.y * LOG2E) +
             __builtin_exp2f(a0.z * LOG2E) + __builtin_exp2f(a0.w * LOG2E) +
             __builtin_exp2f(a1.x * LOG2E) + __builtin_exp2f(a1.y * LOG2E) +
             __builtin_exp2f(a1.z * LOG2E) + __builtin_exp2f(a1.w * LOG2E);
  float s1 = __builtin_exp2f(c0.x * LOG2E) + __builtin_exp2f(c0.y * LOG2E) +
             __builtin_exp2f(c0.z * LOG2E) + __builtin_exp2f(c0.w * LOG2E) +
             __builtin_exp2f(c1.x * LOG2E) + __builtin_exp2f(c1.y * LOG2E) +
             __builtin_exp2f(c1.z * LOG2E) + __builtin_exp2f(c1.w * LOG2E);
#pragma unroll
  for (int s = 32; s >= 1; s >>= 1) {
    s0 += __shfl_xor(s0, s);
    s1 += __shfl_xor(s1, s);
  }

#define EMIT_ROW(r, v0, v1, ssum)                                             \
  {                                                                           \
    const int u = (r) % U_;                                                   \
    const int bt = (r) / U_;                                                  \
    const int t = bt % T_;                                                    \
    const int b = bt / T_;                                                    \
    float emitv = 0.0f;                                                       \
    if (u < UM1) {                                                            \
      int e = labels[b * UM1 + u]; /* in [1, V) */                            \
      floatx4 sel = (e < 256) ? v0 : v1;                                      \
      int k = e & 3;                                                          \
      float cand =                                                            \
          (k == 0) ? sel.x : (k == 1) ? sel.y : (k == 2) ? sel.z : sel.w;     \
      emitv = __shfl(cand, (e & 255) >> 2);                                   \
    }                                                                         \
    if (lane == 0) {                                                          \
      const float rs = CS * __builtin_amdgcn_rcpf(ssum);                      \
      blankD[((size_t)b * DALLOC + (t + u + 1)) * DSTR + u] =                 \
          __builtin_exp2f(v0.x * LOG2E) * rs;                                 \
      if (u < UM1)                                                            \
        emitD[((size_t)b * DALLOC + (t + u + 1)) * DSTR + (u + 1)] =          \
            __builtin_exp2f(emitv * LOG2E) * rs;                              \
    }                                                                         \
  }

  EMIT_ROW(r0, a0, a1, s0)
  EMIT_ROW(r1, c0, c1, s1)
#undef EMIT_ROW
}

// Bidirectional linear-domain DP. Blocks 0..7: forward alpha to diagonal
// dmid; blocks 8..15: backward beta down to dmid. One FMA-class chain per
// stage; power-of-2 renorm per 32-stage chunk. Each block writes its meeting
// state (128 floats + scale) to ws.
__global__ __launch_bounds__(64, 1) void dp_kernel(
    const float* __restrict__ blankD, const float* __restrict__ emitD,
    const int* __restrict__ act_lens, const int* __restrict__ label_lens,
    float* __restrict__ stateA, float* __restrict__ stateB) {
  __shared__ float lds[2][2][CH][DSTR];  // 128 KB
  const int bid = blockIdx.x;
  const int b = bid & 7;
  const bool fwd = (bid < 8);
  const int lane = threadIdx.x;
  const int tl1 = act_lens[b] - 1;
  const int ulen = label_lens[b];
  const int dtar = tl1 + ulen;
  const int dmid = dtar >> 1;
  const floatx4* g4B = (const floatx4*)(blankD + (size_t)b * DALLOC * DSTR);
  const floatx4* g4E = (const floatx4*)(emitD + (size_t)b * DALLOC * DSTR);
  floatx4 rB[16], rE[16];
  float xE, xO, S = 0.0f;

  if (fwd) {
    // ---------------- forward: alpha, diagonals 1..dmid ----------------
#pragma unroll
    for (int j = 0; j < 16; ++j) {
      rB[j] = g4B[32 + j * 64 + lane];  // chunk 0 = rows 1..32
      rE[j] = g4E[32 + j * 64 + lane];
    }
    {
      floatx4* lB4 = (floatx4*)&lds[0][0][0][0];
      floatx4* lE4 = (floatx4*)&lds[0][1][0][0];
#pragma unroll
      for (int j = 0; j < 16; ++j) {
        lB4[j * 64 + lane] = rB[j];
        lE4[j * 64 + lane] = rE[j];
      }
    }
    xE = (lane == 0) ? 1.0f : 0.0f;  // alpha[0,0] = 1 at diagonal 0
    xO = 0.0f;
    for (int c = 0; c < NCHD; ++c) {
      const int buf = c & 1;
      const int nb = ((c + 1) * CH + 1) * 32;
#pragma unroll
      for (int j = 0; j < 16; ++j) {
        rB[j] = g4B[(size_t)nb + j * 64 + lane];
        rE[j] = g4E[(size_t)nb + j * 64 + lane];
      }
      const floatx2* lB2 = (const floatx2*)&lds[buf][0][0][0];
      const floatx2* lE2 = (const floatx2*)&lds[buf][1][0][0];
      floatx2 pB[8], pE[8];
#pragma unroll
      for (int k = 0; k < 8; ++k) {
        pB[k] = lB2[k * 64 + lane];
        pE[k] = lE2[k * 64 + lane];
      }
      const int dbase = c * CH + 1;
#pragma unroll
      for (int k = 0; k < CH; ++k) {
        const int d = dbase + k;
        const floatx2 Bv = pB[k & 7];
        const floatx2 Ev = pE[k & 7];
        if (k + 8 < CH) {
          pB[k & 7] = lB2[(k + 8) * 64 + lane];
          pE[k & 7] = lE2[(k + 8) * 64 + lane];
        }
        const float xm1E = wave_shr1_zero(xO);  // col uE-1, prev diagonal
        const float nxE = __builtin_fmaf(xE, Bv.x, xm1E * Ev.x);
        const float nxO = __builtin_fmaf(xO, Bv.y, xE * Ev.y);
        const bool go = (d <= dmid);  // freeze at meeting diagonal
        xE = go ? nxE : xE;
        xO = go ? nxO : xO;
      }
      float m = fmaxf(xE, xO);
#pragma unroll
      for (int s = 32; s >= 1; s >>= 1) m = fmaxf(m, __shfl_xor(m, s));
      if (m > 0.0f) {
        const float ex = floorf(__builtin_log2f(m));
        const float sc = __builtin_exp2f(-ex);
        xE *= sc;
        xO *= sc;
        S += ex;
      }
      floatx4* wB4 = (floatx4*)&lds[buf ^ 1][0][0][0];
      floatx4* wE4 = (floatx4*)&lds[buf ^ 1][1][0][0];
#pragma unroll
      for (int j = 0; j < 16; ++j) {
        wB4[j * 64 + lane] = rB[j];
        wE4[j * 64 + lane] = rE[j];
      }
    }
    float* sA = stateA + b * 132;
    ((floatx2*)sA)[lane] = floatx2{xE, xO};
    if (lane == 0) sA[128] = S;
  } else {
    // ---------------- backward: beta, diagonals dtar-1..dmid ----------------
    // Stage s computes beta[diag m], m = dtar-1-s, reading staged row m+1.
    // beta_new[u] = Bl[u]*beta[u] + Em_row[u+1]*beta[u+1]; the odd column's
    // (u+1) term lives in lane l+1 as Ev.x*xE -> one DPP wave_shl1.
    const int R00 = dtar - 31;  // chunk 0 rows [dtar-31, dtar]
#pragma unroll
    for (int j = 0; j < 16; ++j) {
      rB[j] = g4B[(size_t)R00 * 32 + j * 64 + lane];
      rE[j] = g4E[(size_t)R00 * 32 + j * 64 + lane];
    }
    {
      floatx4* lB4 = (floatx4*)&lds[0][0][0][0];
      floatx4* lE4 = (floatx4*)&lds[0][1][0][0];
#pragma unroll
      for (int j = 0; j < 16; ++j) {
        lB4[j * 64 + lane] = rB[j];
        lE4[j * 64 + lane] = rE[j];
      }
    }
    // Seed: beta[diag dtar] = staged blank[tl1, ulen] at column ulen.
    const float seed = blankD[((size_t)b * DALLOC + dtar + 1) * DSTR + ulen];
    xE = (lane == (ulen >> 1) && !(ulen & 1)) ? seed : 0.0f;
    xO = (lane == (ulen >> 1) && (ulen & 1)) ? seed : 0.0f;
    const int smax = dtar - 1 - dmid;  // last live stage
    for (int c = 0; c < NCHD; ++c) {
      const int buf = c & 1;
      const int R0n = max(R00 - 32 * (c + 1), 0);  // next chunk base row
#pragma unroll
      for (int j = 0; j < 16; ++j) {
        rB[j] = g4B[(size_t)R0n * 32 + j * 64 + lane];
        rE[j] = g4E[(size_t)R0n * 32 + j * 64 + lane];
      }
      const floatx2* lB2 = (const floatx2*)&lds[buf][0][0][0];
      const floatx2* lE2 = (const floatx2*)&lds[buf][1][0][0];
      floatx2 pB[8], pE[8];
#pragma unroll
      for (int k = 0; k < 8; ++k) {  // slots descending: 31..24
        pB[k] = lB2[(31 - k) * 64 + lane];
        pE[k] = lE2[(31 - k) * 64 + lane];
      }
#pragma unroll
      for (int k = 0; k < CH; ++k) {
        const int s = c * CH + k;
        const floatx2 Bv = pB[k & 7];
        const floatx2 Ev = pE[k & 7];
        if (k + 8 < CH) {
          pB[k & 7] = lB2[(31 - (k + 8)) * 64 + lane];
          pE[k & 7] = lE2[(31 - (k + 8)) * 64 + lane];
        }
        const float tO = wave_shl1_zero(Ev.x * xE);  // lane l+1: Em*beta
        const float nxE = __builtin_fmaf(xE, Bv.x, Ev.y * xO);
        const float nxO = __builtin_fmaf(xO, Bv.y, tO);
        const bool go = (s <= smax);
        xE = go ? nxE : xE;
        xO = go ? nxO : xO;
      }
      float m = fmaxf(xE, xO);
#pragma unroll
      for (int s2 = 32; s2 >= 1; s2 >>= 1) m = fmaxf(m, __shfl_xor(m, s2));
      if (m > 0.0f) {
        const float ex = floorf(__builtin_log2f(m));
        const float sc = __builtin_exp2f(-ex);
        xE *= sc;
        xO *= sc;
        S += ex;
      }
      floatx4* wB4 = (floatx4*)&lds[buf ^ 1][0][0][0];
      floatx4* wE4 = (floatx4*)&lds[buf ^ 1][1][0][0];
#pragma unroll
      for (int j = 0; j < 16; ++j) {
        wB4[j * 64 + lane] = rB[j];
        wE4[j * 64 + lane] = rE[j];
      }
    }
    float* sB = stateB + b * 132;
    ((floatx2*)sB)[lane] = floatx2{xE, xO};
    if (lane == 0) sB[128] = S;
  }
}

// Combine: P = sum_u alpha_hat[dmid,u] * beta_hat[dmid,u];
// log2 P = log2(sum) + Sa + Sb - 9*(dtar+1).
__global__ __launch_bounds__(64) void combine_kernel(
    const float* __restrict__ stateA, const float* __restrict__ stateB,
    const int* __restrict__ act_lens, const int* __restrict__ label_lens,
    float* __restrict__ out) {
  const int b = blockIdx.x;
  const int lane = threadIdx.x;
  const float* sA = stateA + b * 132;
  const float* sB = stateB + b * 132;
  const floatx2 a = ((const floatx2*)sA)[lane];
  const floatx2 bb = ((const floatx2*)sB)[lane];
  float p = a.x * bb.x + a.y * bb.y;
#pragma unroll
  for (int s = 32; s >= 1; s >>= 1) p += __shfl_xor(p, s);
  if (lane == 0) {
    const int dtar = act_lens[b] - 1 + label_lens[b];
    out[b] = -((__builtin_log2f(p) + sA[128] + sB[128] -
                9.0f * (float)(dtar + 1)) *
               LN2);
  }
}

extern "C" void kernel_launch(void* const* d_in, const int* in_sizes, int n_in,
                              void* d_out, int out_size, void* d_ws, size_t ws_size,
                              hipStream_t stream) {
  const float* acts = (const float*)d_in[0];
  const int* labels = (const int*)d_in[1];
  const int* act_lens = (const int*)d_in[2];
  const int* label_lens = (const int*)d_in[3];
  float* out = (float*)d_out;
  float* blankD = (float*)d_ws;                         // B*DALLOC*DSTR floats
  float* emitD = blankD + (size_t)B_ * DALLOC * DSTR;   // B*DALLOC*DSTR floats
  float* stateA = emitD + (size_t)B_ * DALLOC * DSTR;   // B*132 floats
  float* stateB = stateA + B_ * 132;                    // B*132 floats
  // Zero staging arrays: unwritten slots must be the additive identity.
  hipMemsetAsync(blankD, 0, (size_t)2 * B_ * DALLOC * DSTR * sizeof(float),
                 stream);
  const int nwaves2 = B_ * T_ * U_ / 2;
  lse_kernel<<<nwaves2 / 4, 256, 0, stream>>>(acts, labels, blankD, emitD);
  dp_kernel<<<16, 64, 0, stream>>>(blankD, emitD, act_lens, label_lens,
                                   stateA, stateB);
  combine_kernel<<<B_, 64, 0, stream>>>(stateA, stateB, act_lens, label_lens,
                                        out);
}

// Round 14
// 94.580 us; speedup vs baseline: 53.6955x; 1.0105x over previous
//
#include <hip/hip_runtime.h>

#define B_ 8
#define T_ 256
#define U_ 101
#define V_ 512
#define UM1 (U_ - 1)
#define DSTR 128    // floats per diagonal row (u-index stride)
#define DALLOC 488  // diagonals allocated
#define CH 32       // DP stages per LDS chunk
#define NCHD 6      // chunks per direction (6*32 = 192 >= ceil(355/2)+1)
#define CS 512.0f   // 2^9 per-step growth factor baked into staged probs
#define LOG2E 1.4426950408889634f
#define LN2 0.6931471805599453f

typedef float floatx4 __attribute__((ext_vector_type(4)));
typedef float floatx2 __attribute__((ext_vector_type(2)));

// DPP move with bound_ctrl=1 (out-of-range lanes read 0).
#define DPPMOV(x, ctrl)                                                     \
  __int_as_float(__builtin_amdgcn_update_dpp(0, __float_as_int(x), (ctrl),  \
                                             0xF, 0xF, true))

__device__ __forceinline__ float readlane63(float x) {
  return __int_as_float(__builtin_amdgcn_readlane(__float_as_int(x), 63));
}
// Full-wave sum via DPP (VALU-latency); result valid in lane 63.
__device__ __forceinline__ float wave_sum63(float x) {
  x += DPPMOV(x, 0x111);  // row_shr:1
  x += DPPMOV(x, 0x112);  // row_shr:2
  x += DPPMOV(x, 0x114);  // row_shr:4
  x += DPPMOV(x, 0x118);  // row_shr:8
  x += DPPMOV(x, 0x142);  // row_bcast:15
  x += DPPMOV(x, 0x143);  // row_bcast:31
  return x;
}
// Full-wave max via DPP (nonnegative inputs); result valid in lane 63.
__device__ __forceinline__ float wave_max63(float x) {
  x = fmaxf(x, DPPMOV(x, 0x111));
  x = fmaxf(x, DPPMOV(x, 0x112));
  x = fmaxf(x, DPPMOV(x, 0x114));
  x = fmaxf(x, DPPMOV(x, 0x118));
  x = fmaxf(x, DPPMOV(x, 0x142));
  x = fmaxf(x, DPPMOV(x, 0x143));
  return x;
}
// lane n <- lane n-1 (DPP wave_shr:1). Lane 0 <- 0 (additive identity).
__device__ __forceinline__ float wave_shr1_zero(float x) {
  int r = __builtin_amdgcn_update_dpp(0, __float_as_int(x), 0x138, 0xF, 0xF,
                                      false);
  return __int_as_float(r);
}
// lane n <- lane n+1 (DPP wave_shl:1). Lane 63 <- 0.
__device__ __forceinline__ float wave_shl1_zero(float x) {
  int r = __builtin_amdgcn_update_dpp(0, __float_as_int(x), 0x130, 0xF, 0xF,
                                      false);
  return __int_as_float(r);
}

// Two rows of V=512 logits per wave, linear in acts memory order. Max-free
// softmax denominator (DPP reduction, no LDS round-trips); stores LINEAR-
// domain scaled probs diagonal-major:
//   blankD[b][t+u+1][u]   = e^blank_logit / sum * 2^9
//   emitD [b][t+u+1][u+1] = e^label_logit / sum * 2^9
// Unwritten slots are pre-zeroed (memset) = additive identity.
__global__ __launch_bounds__(256) void lse_kernel(
    const float* __restrict__ acts, const int* __restrict__ labels,
    float* __restrict__ blankD, float* __restrict__ emitD) {
  const int wv = blockIdx.x * 4 + (threadIdx.x >> 6);
  const int lane = threadIdx.x & 63;
  const int r0 = wv * 2;  // row = (b*T + t)*U + u
  const int r1 = r0 + 1;
  const floatx4* p0 = (const floatx4*)(acts + (size_t)r0 * V_);
  const floatx4* p1 = (const floatx4*)(acts + (size_t)r1 * V_);
  floatx4 a0 = p0[lane];
  floatx4 a1 = p0[lane + 64];
  floatx4 c0 = p1[lane];
  floatx4 c1 = p1[lane + 64];
  float s0 = __builtin_exp2f(a0.x * LOG2E) + __builtin_exp2f(a0.y * LOG2E) +
             __builtin_exp2f(a0.z * LOG2E) + __builtin_exp2f(a0.w * LOG2E) +
             __builtin_exp2f(a1.x * LOG2E) + __builtin_exp2f(a1.y * LOG2E) +
             __builtin_exp2f(a1.z * LOG2E) + __builtin_exp2f(a1.w * LOG2E);
  float s1 = __builtin_exp2f(c0.x * LOG2E) + __builtin_exp2f(c0.y * LOG2E) +
             __builtin_exp2f(c0.z * LOG2E) + __builtin_exp2f(c0.w * LOG2E) +
             __builtin_exp2f(c1.x * LOG2E) + __builtin_exp2f(c1.y * LOG2E) +
             __builtin_exp2f(c1.z * LOG2E) + __builtin_exp2f(c1.w * LOG2E);
  s0 = readlane63(wave_sum63(s0));  // uniform across the wave
  s1 = readlane63(wave_sum63(s1));

#define EMIT_ROW(r, v0, v1, ssum)                                             \
  {                                                                           \
    const int u = (r) % U_;                                                   \
    const int bt = (r) / U_;                                                  \
    const int t = bt % T_;                                                    \
    const int b = bt / T_;                                                    \
    float emitv = 0.0f;                                                       \
    if (u < UM1) {                                                            \
      int e = labels[b * UM1 + u]; /* in [1, V) */                            \
      floatx4 sel = (e < 256) ? v0 : v1;                                      \
      int k = e & 3;                                                          \
      float cand =                                                            \
          (k == 0) ? sel.x : (k == 1) ? sel.y : (k == 2) ? sel.z : sel.w;     \
      emitv = __shfl(cand, (e & 255) >> 2);                                   \
    }                                                                         \
    if (lane == 0) {                                                          \
      const float rs = CS * __builtin_amdgcn_rcpf(ssum);                      \
      blankD[((size_t)b * DALLOC + (t + u + 1)) * DSTR + u] =                 \
          __builtin_exp2f(v0.x * LOG2E) * rs;                                 \
      if (u < UM1)                                                            \
        emitD[((size_t)b * DALLOC + (t + u + 1)) * DSTR + (u + 1)] =          \
            __builtin_exp2f(emitv * LOG2E) * rs;                              \
    }                                                                         \
  }

  EMIT_ROW(r0, a0, a1, s0)
  EMIT_ROW(r1, c0, c1, s1)
#undef EMIT_ROW
}

// Bidirectional linear-domain DP. Blocks 0..7: forward alpha; 8..15:
// backward beta. Recurrence chain is pure dpp+mul+fma; the meeting-diagonal
// state is CAPTURED off-chain (no in-chain freeze masks). Power-of-2 renorm
// per chunk via DPP max-reduce.
__global__ __launch_bounds__(64, 1) void dp_kernel(
    const float* __restrict__ blankD, const float* __restrict__ emitD,
    const int* __restrict__ act_lens, const int* __restrict__ label_lens,
    float* __restrict__ stateA, float* __restrict__ stateB) {
  __shared__ float lds[2][2][CH][DSTR];  // 128 KB
  const int bid = blockIdx.x;
  const int b = bid & 7;
  const bool fwd = (bid < 8);
  const int lane = threadIdx.x;
  const int tl1 = act_lens[b] - 1;
  const int ulen = label_lens[b];
  const int dtar = tl1 + ulen;
  const int dmid = dtar >> 1;
  const floatx4* g4B = (const floatx4*)(blankD + (size_t)b * DALLOC * DSTR);
  const floatx4* g4E = (const floatx4*)(emitD + (size_t)b * DALLOC * DSTR);
  floatx4 rB[16], rE[16];
  float xE, xO, S = 0.0f, cE = 0.0f, cO = 0.0f, capS = 0.0f;

  if (fwd) {
    // ---------------- forward: alpha; capture at diagonal dmid ------------
    const int ccap = (dmid - 1) >> 5;  // chunk containing d == dmid
#pragma unroll
    for (int j = 0; j < 16; ++j) {
      rB[j] = g4B[32 + j * 64 + lane];  // chunk 0 = rows 1..32
      rE[j] = g4E[32 + j * 64 + lane];
    }
    {
      floatx4* lB4 = (floatx4*)&lds[0][0][0][0];
      floatx4* lE4 = (floatx4*)&lds[0][1][0][0];
#pragma unroll
      for (int j = 0; j < 16; ++j) {
        lB4[j * 64 + lane] = rB[j];
        lE4[j * 64 + lane] = rE[j];
      }
    }
    xE = (lane == 0) ? 1.0f : 0.0f;  // alpha[0,0] = 1 at diagonal 0
    xO = 0.0f;
    for (int c = 0; c < NCHD; ++c) {
      const int buf = c & 1;
      const int nb = ((c + 1) * CH + 1) * 32;
#pragma unroll
      for (int j = 0; j < 16; ++j) {
        rB[j] = g4B[(size_t)nb + j * 64 + lane];
        rE[j] = g4E[(size_t)nb + j * 64 + lane];
      }
      const floatx2* lB2 = (const floatx2*)&lds[buf][0][0][0];
      const floatx2* lE2 = (const floatx2*)&lds[buf][1][0][0];
      floatx2 pB[8], pE[8];
#pragma unroll
      for (int k = 0; k < 8; ++k) {
        pB[k] = lB2[k * 64 + lane];
        pE[k] = lE2[k * 64 + lane];
      }
      const int dbase = c * CH + 1;
#pragma unroll
      for (int k = 0; k < CH; ++k) {
        const int d = dbase + k;
        const floatx2 Bv = pB[k & 7];
        const floatx2 Ev = pE[k & 7];
        if (k + 8 < CH) {
          pB[k & 7] = lB2[(k + 8) * 64 + lane];
          pE[k & 7] = lE2[(k + 8) * 64 + lane];
        }
        const float xm1E = wave_shr1_zero(xO);  // col uE-1, prev diagonal
        const float nxE = __builtin_fmaf(xE, Bv.x, xm1E * Ev.x);
        const float nxO = __builtin_fmaf(xO, Bv.y, xE * Ev.y);
        const bool cap = (d == dmid);  // off-chain capture
        cE = cap ? nxE : cE;
        cO = cap ? nxO : cO;
        xE = nxE;
        xO = nxO;
      }
      if (c == ccap) capS = S;  // scales applied before the capture chunk
      float m = readlane63(wave_max63(fmaxf(xE, xO)));
      if (m > 0.0f) {
        const float ex = floorf(__builtin_log2f(m));
        const float sc = __builtin_exp2f(-ex);
        xE *= sc;
        xO *= sc;
        S += ex;
      }
      floatx4* wB4 = (floatx4*)&lds[buf ^ 1][0][0][0];
      floatx4* wE4 = (floatx4*)&lds[buf ^ 1][1][0][0];
#pragma unroll
      for (int j = 0; j < 16; ++j) {
        wB4[j * 64 + lane] = rB[j];
        wE4[j * 64 + lane] = rE[j];
      }
    }
    float* sA = stateA + b * 132;
    ((floatx2*)sA)[lane] = floatx2{cE, cO};
    if (lane == 0) sA[128] = capS;
  } else {
    // ---------------- backward: beta; capture at stage smax ---------------
    // Stage s computes beta[diag m], m = dtar-1-s, reading staged row m+1.
    const int smax = dtar - 1 - dmid;
    const int ccap = smax >> 5;
    const int R00 = dtar - 31;  // chunk 0 rows [dtar-31, dtar]
#pragma unroll
    for (int j = 0; j < 16; ++j) {
      rB[j] = g4B[(size_t)R00 * 32 + j * 64 + lane];
      rE[j] = g4E[(size_t)R00 * 32 + j * 64 + lane];
    }
    {
      floatx4* lB4 = (floatx4*)&lds[0][0][0][0];
      floatx4* lE4 = (floatx4*)&lds[0][1][0][0];
#pragma unroll
      for (int j = 0; j < 16; ++j) {
        lB4[j * 64 + lane] = rB[j];
        lE4[j * 64 + lane] = rE[j];
      }
    }
    const float seed = blankD[((size_t)b * DALLOC + dtar + 1) * DSTR + ulen];
    xE = (lane == (ulen >> 1) && !(ulen & 1)) ? seed : 0.0f;
    xO = (lane == (ulen >> 1) && (ulen & 1)) ? seed : 0.0f;
    for (int c = 0; c < NCHD; ++c) {
      const int buf = c & 1;
      const int R0n = max(R00 - 32 * (c + 1), 0);
#pragma unroll
      for (int j = 0; j < 16; ++j) {
        rB[j] = g4B[(size_t)R0n * 32 + j * 64 + lane];
        rE[j] = g4E[(size_t)R0n * 32 + j * 64 + lane];
      }
      const floatx2* lB2 = (const floatx2*)&lds[buf][0][0][0];
      const floatx2* lE2 = (const floatx2*)&lds[buf][1][0][0];
      floatx2 pB[8], pE[8];
#pragma unroll
      for (int k = 0; k < 8; ++k) {  // slots descending: 31..24
        pB[k] = lB2[(31 - k) * 64 + lane];
        pE[k] = lE2[(31 - k) * 64 + lane];
      }
#pragma unroll
      for (int k = 0; k < CH; ++k) {
        const int s = c * CH + k;
        const floatx2 Bv = pB[k & 7];
        const floatx2 Ev = pE[k & 7];
        if (k + 8 < CH) {
          pB[k & 7] = lB2[(31 - (k + 8)) * 64 + lane];
          pE[k & 7] = lE2[(31 - (k + 8)) * 64 + lane];
        }
        const float tO = wave_shl1_zero(Ev.x * xE);  // lane l+1: Em*beta
        const float nxE = __builtin_fmaf(xE, Bv.x, Ev.y * xO);
        const float nxO = __builtin_fmaf(xO, Bv.y, tO);
        const bool cap = (s == smax);  // off-chain capture
        cE = cap ? nxE : cE;
        cO = cap ? nxO : cO;
        xE = nxE;
        xO = nxO;
      }
      if (c == ccap) capS = S;
      float m = readlane63(wave_max63(fmaxf(xE, xO)));
      if (m > 0.0f) {
        const float ex = floorf(__builtin_log2f(m));
        const float sc = __builtin_exp2f(-ex);
        xE *= sc;
        xO *= sc;
        S += ex;
      }
      floatx4* wB4 = (floatx4*)&lds[buf ^ 1][0][0][0];
      floatx4* wE4 = (floatx4*)&lds[buf ^ 1][1][0][0];
#pragma unroll
      for (int j = 0; j < 16; ++j) {
        wB4[j * 64 + lane] = rB[j];
        wE4[j * 64 + lane] = rE[j];
      }
    }
    float* sB = stateB + b * 132;
    ((floatx2*)sB)[lane] = floatx2{cE, cO};
    if (lane == 0) sB[128] = capS;
  }
}

// Combine: P = sum_u alpha_hat[dmid,u] * beta_hat[dmid,u];
// log2 P = log2(sum) + Sa + Sb - 9*(dtar+1).
__global__ __launch_bounds__(64) void combine_kernel(
    const float* __restrict__ stateA, const float* __restrict__ stateB,
    const int* __restrict__ act_lens, const int* __restrict__ label_lens,
    float* __restrict__ out) {
  const int b = blockIdx.x;
  const int lane = threadIdx.x;
  const float* sA = stateA + b * 132;
  const float* sB = stateB + b * 132;
  const floatx2 a = ((const floatx2*)sA)[lane];
  const floatx2 bb = ((const floatx2*)sB)[lane];
  float p = readlane63(wave_sum63(a.x * bb.x + a.y * bb.y));
  if (lane == 0) {
    const int dtar = act_lens[b] - 1 + label_lens[b];
    out[b] = -((__builtin_log2f(p) + sA[128] + sB[128] -
                9.0f * (float)(dtar + 1)) *
               LN2);
  }
}

extern "C" void kernel_launch(void* const* d_in, const int* in_sizes, int n_in,
                              void* d_out, int out_size, void* d_ws, size_t ws_size,
                              hipStream_t stream) {
  const float* acts = (const float*)d_in[0];
  const int* labels = (const int*)d_in[1];
  const int* act_lens = (const int*)d_in[2];
  const int* label_lens = (const int*)d_in[3];
  float* out = (float*)d_out;
  float* blankD = (float*)d_ws;                         // B*DALLOC*DSTR floats
  float* emitD = blankD + (size_t)B_ * DALLOC * DSTR;   // B*DALLOC*DSTR floats
  float* stateA = emitD + (size_t)B_ * DALLOC * DSTR;   // B*132 floats
  float* stateB = stateA + B_ * 132;                    // B*132 floats
  hipMemsetAsync(blankD, 0, (size_t)2 * B_ * DALLOC * DSTR * sizeof(float),
                 stream);
  const int nwaves2 = B_ * T_ * U_ / 2;
  lse_kernel<<<nwaves2 / 4, 256, 0, stream>>>(acts, labels, blankD, emitD);
  dp_kernel<<<16, 64, 0, stream>>>(blankD, emitD, act_lens, label_lens,
                                   stateA, stateB);
  combine_kernel<<<B_, 64, 0, stream>>>(stateA, stateB, act_lens, label_lens,
                                        out);
}

// Round 15
// 93.894 us; speedup vs baseline: 54.0879x; 1.0073x over previous
//
#include <hip/hip_runtime.h>

#define B_ 8
#define T_ 256
#define U_ 101
#define V_ 512
#define UM1 (U_ - 1)
#define DSTR 128    // floats per diagonal row (u-index stride)
#define DALLOC 360  // diagonals allocated (max row read = 356)
#define CH 32       // DP stages per LDS chunk
#define NCHD 6      // chunks per direction (6*32 = 192 >= ceil(355/2)+1)
#define CS 512.0f   // 2^9 per-step growth factor baked into staged probs
#define LOG2E 1.4426950408889634f
#define LN2 0.6931471805599453f

typedef float floatx4 __attribute__((ext_vector_type(4)));
typedef float floatx2 __attribute__((ext_vector_type(2)));

// DPP move with bound_ctrl=1 (out-of-range lanes read 0).
#define DPPMOV(x, ctrl)                                                     \
  __int_as_float(__builtin_amdgcn_update_dpp(0, __float_as_int(x), (ctrl),  \
                                             0xF, 0xF, true))

__device__ __forceinline__ float readlane63(float x) {
  return __int_as_float(__builtin_amdgcn_readlane(__float_as_int(x), 63));
}
// Full-wave sum via DPP (VALU-latency); result valid in lane 63.
__device__ __forceinline__ float wave_sum63(float x) {
  x += DPPMOV(x, 0x111);  // row_shr:1
  x += DPPMOV(x, 0x112);  // row_shr:2
  x += DPPMOV(x, 0x114);  // row_shr:4
  x += DPPMOV(x, 0x118);  // row_shr:8
  x += DPPMOV(x, 0x142);  // row_bcast:15
  x += DPPMOV(x, 0x143);  // row_bcast:31
  return x;
}
// Full-wave max via DPP (nonnegative inputs); result valid in lane 63.
__device__ __forceinline__ float wave_max63(float x) {
  x = fmaxf(x, DPPMOV(x, 0x111));
  x = fmaxf(x, DPPMOV(x, 0x112));
  x = fmaxf(x, DPPMOV(x, 0x114));
  x = fmaxf(x, DPPMOV(x, 0x118));
  x = fmaxf(x, DPPMOV(x, 0x142));
  x = fmaxf(x, DPPMOV(x, 0x143));
  return x;
}
// lane n <- lane n-1 (DPP wave_shr:1). Lane 0 <- 0 (additive identity).
__device__ __forceinline__ float wave_shr1_zero(float x) {
  int r = __builtin_amdgcn_update_dpp(0, __float_as_int(x), 0x138, 0xF, 0xF,
                                      false);
  return __int_as_float(r);
}
// lane n <- lane n+1 (DPP wave_shl:1). Lane 63 <- 0.
__device__ __forceinline__ float wave_shl1_zero(float x) {
  int r = __builtin_amdgcn_update_dpp(0, __float_as_int(x), 0x130, 0xF, 0xF,
                                      false);
  return __int_as_float(r);
}

// Two rows of V=512 logits per wave, linear in acts memory order. Max-free
// softmax denominator (DPP reduction); stores LINEAR-domain scaled probs
// diagonal-major:
//   blankD[b][t+u+1][u]   = e^blank_logit / sum * 2^9
//   emitD [b][t+u+1][u+1] = e^label_logit / sum * 2^9
// Unwritten slots are pre-zeroed (memset) = additive identity.
__global__ __launch_bounds__(256) void lse_kernel(
    const float* __restrict__ acts, const int* __restrict__ labels,
    float* __restrict__ blankD, float* __restrict__ emitD) {
  const int wv = blockIdx.x * 4 + (threadIdx.x >> 6);
  const int lane = threadIdx.x & 63;
  const int r0 = wv * 2;  // row = (b*T + t)*U + u
  const int r1 = r0 + 1;
  const floatx4* p0 = (const floatx4*)(acts + (size_t)r0 * V_);
  const floatx4* p1 = (const floatx4*)(acts + (size_t)r1 * V_);
  floatx4 a0 = p0[lane];
  floatx4 a1 = p0[lane + 64];
  floatx4 c0 = p1[lane];
  floatx4 c1 = p1[lane + 64];
  float s0 = __builtin_exp2f(a0.x * LOG2E) + __builtin_exp2f(a0.y * LOG2E) +
             __builtin_exp2f(a0.z * LOG2E) + __builtin_exp2f(a0.w * LOG2E) +
             __builtin_exp2f(a1.x * LOG2E) + __builtin_exp2f(a1.y * LOG2E) +
             __builtin_exp2f(a1.z * LOG2E) + __builtin_exp2f(a1.w * LOG2E);
  float s1 = __builtin_exp2f(c0.x * LOG2E) + __builtin_exp2f(c0.y * LOG2E) +
             __builtin_exp2f(c0.z * LOG2E) + __builtin_exp2f(c0.w * LOG2E) +
             __builtin_exp2f(c1.x * LOG2E) + __builtin_exp2f(c1.y * LOG2E) +
             __builtin_exp2f(c1.z * LOG2E) + __builtin_exp2f(c1.w * LOG2E);
  s0 = readlane63(wave_sum63(s0));  // uniform across the wave
  s1 = readlane63(wave_sum63(s1));

#define EMIT_ROW(r, v0, v1, ssum)                                             \
  {                                                                           \
    const int u = (r) % U_;                                                   \
    const int bt = (r) / U_;                                                  \
    const int t = bt % T_;                                                    \
    const int b = bt / T_;                                                    \
    float emitv = 0.0f;                                                       \
    if (u < UM1) {                                                            \
      int e = labels[b * UM1 + u]; /* in [1, V) */                            \
      floatx4 sel = (e < 256) ? v0 : v1;                                      \
      int k = e & 3;                                                          \
      float cand =                                                            \
          (k == 0) ? sel.x : (k == 1) ? sel.y : (k == 2) ? sel.z : sel.w;     \
      emitv = __shfl(cand, (e & 255) >> 2);                                   \
    }                                                                         \
    if (lane == 0) {                                                          \
      const float rs = CS * __builtin_amdgcn_rcpf(ssum);                      \
      blankD[((size_t)b * DALLOC + (t + u + 1)) * DSTR + u] =                 \
          __builtin_exp2f(v0.x * LOG2E) * rs;                                 \
      if (u < UM1)                                                            \
        emitD[((size_t)b * DALLOC + (t + u + 1)) * DSTR + (u + 1)] =          \
            __builtin_exp2f(emitv * LOG2E) * rs;                              \
    }                                                                         \
  }

  EMIT_ROW(r0, a0, a1, s0)
  EMIT_ROW(r1, c0, c1, s1)
#undef EMIT_ROW
}

// Bidirectional linear-domain DP with fused combine. Blocks 0..7: forward
// alpha; 8..15: backward beta. Each block writes its meeting state; the
// SECOND finisher per example (flag handshake, order-independent result)
// computes the final loss. Recurrence chain is pure dpp+mul+fma.
__global__ __launch_bounds__(64, 1) void dp_kernel(
    const float* __restrict__ blankD, const float* __restrict__ emitD,
    const int* __restrict__ act_lens, const int* __restrict__ label_lens,
    float* __restrict__ stateA, float* __restrict__ stateB,
    int* __restrict__ flags, float* __restrict__ out) {
  __shared__ float lds[2][2][CH][DSTR];  // 128 KB
  const int bid = blockIdx.x;
  const int b = bid & 7;
  const bool fwd = (bid < 8);
  const int lane = threadIdx.x;
  const int tl1 = act_lens[b] - 1;
  const int ulen = label_lens[b];
  const int dtar = tl1 + ulen;
  const int dmid = dtar >> 1;
  const floatx4* g4B = (const floatx4*)(blankD + (size_t)b * DALLOC * DSTR);
  const floatx4* g4E = (const floatx4*)(emitD + (size_t)b * DALLOC * DSTR);
  floatx4 rB[16], rE[16];
  float xE, xO, S = 0.0f, cE = 0.0f, cO = 0.0f, capS = 0.0f;

  if (fwd) {
    // ---------------- forward: alpha; capture at diagonal dmid ------------
    const int ccap = (dmid - 1) >> 5;  // chunk containing d == dmid
#pragma unroll
    for (int j = 0; j < 16; ++j) {
      rB[j] = g4B[32 + j * 64 + lane];  // chunk 0 = rows 1..32
      rE[j] = g4E[32 + j * 64 + lane];
    }
    {
      floatx4* lB4 = (floatx4*)&lds[0][0][0][0];
      floatx4* lE4 = (floatx4*)&lds[0][1][0][0];
#pragma unroll
      for (int j = 0; j < 16; ++j) {
        lB4[j * 64 + lane] = rB[j];
        lE4[j * 64 + lane] = rE[j];
      }
    }
    xE = (lane == 0) ? 1.0f : 0.0f;  // alpha[0,0] = 1 at diagonal 0
    xO = 0.0f;
    for (int c = 0; c < NCHD; ++c) {
      const int buf = c & 1;
      const int nb = ((c + 1) * CH + 1) * 32;
#pragma unroll
      for (int j = 0; j < 16; ++j) {
        rB[j] = g4B[(size_t)nb + j * 64 + lane];
        rE[j] = g4E[(size_t)nb + j * 64 + lane];
      }
      const floatx2* lB2 = (const floatx2*)&lds[buf][0][0][0];
      const floatx2* lE2 = (const floatx2*)&lds[buf][1][0][0];
      floatx2 pB[8], pE[8];
#pragma unroll
      for (int k = 0; k < 8; ++k) {
        pB[k] = lB2[k * 64 + lane];
        pE[k] = lE2[k * 64 + lane];
      }
      const int dbase = c * CH + 1;
#pragma unroll
      for (int k = 0; k < CH; ++k) {
        const int d = dbase + k;
        const floatx2 Bv = pB[k & 7];
        const floatx2 Ev = pE[k & 7];
        if (k + 8 < CH) {
          pB[k & 7] = lB2[(k + 8) * 64 + lane];
          pE[k & 7] = lE2[(k + 8) * 64 + lane];
        }
        const float xm1E = wave_shr1_zero(xO);  // col uE-1, prev diagonal
        const float nxE = __builtin_fmaf(xE, Bv.x, xm1E * Ev.x);
        const float nxO = __builtin_fmaf(xO, Bv.y, xE * Ev.y);
        const bool cap = (d == dmid);  // off-chain capture
        cE = cap ? nxE : cE;
        cO = cap ? nxO : cO;
        xE = nxE;
        xO = nxO;
      }
      if (c == ccap) capS = S;  // scales applied before the capture chunk
      float m = readlane63(wave_max63(fmaxf(xE, xO)));
      if (m > 0.0f) {
        const float ex = floorf(__builtin_log2f(m));
        const float sc = __builtin_exp2f(-ex);
        xE *= sc;
        xO *= sc;
        S += ex;
      }
      floatx4* wB4 = (floatx4*)&lds[buf ^ 1][0][0][0];
      floatx4* wE4 = (floatx4*)&lds[buf ^ 1][1][0][0];
#pragma unroll
      for (int j = 0; j < 16; ++j) {
        wB4[j * 64 + lane] = rB[j];
        wE4[j * 64 + lane] = rE[j];
      }
    }
    float* sA = stateA + b * 132;
    ((floatx2*)sA)[lane] = floatx2{cE, cO};
    if (lane == 0) sA[128] = capS;
  } else {
    // ---------------- backward: beta; capture at stage smax ---------------
    const int smax = dtar - 1 - dmid;
    const int ccap = smax >> 5;
    const int R00 = dtar - 31;  // chunk 0 rows [dtar-31, dtar]
#pragma unroll
    for (int j = 0; j < 16; ++j) {
      rB[j] = g4B[(size_t)R00 * 32 + j * 64 + lane];
      rE[j] = g4E[(size_t)R00 * 32 + j * 64 + lane];
    }
    {
      floatx4* lB4 = (floatx4*)&lds[0][0][0][0];
      floatx4* lE4 = (floatx4*)&lds[0][1][0][0];
#pragma unroll
      for (int j = 0; j < 16; ++j) {
        lB4[j * 64 + lane] = rB[j];
        lE4[j * 64 + lane] = rE[j];
      }
    }
    const float seed = blankD[((size_t)b * DALLOC + dtar + 1) * DSTR + ulen];
    xE = (lane == (ulen >> 1) && !(ulen & 1)) ? seed : 0.0f;
    xO = (lane == (ulen >> 1) && (ulen & 1)) ? seed : 0.0f;
    for (int c = 0; c < NCHD; ++c) {
      const int buf = c & 1;
      const int R0n = max(R00 - 32 * (c + 1), 0);
#pragma unroll
      for (int j = 0; j < 16; ++j) {
        rB[j] = g4B[(size_t)R0n * 32 + j * 64 + lane];
        rE[j] = g4E[(size_t)R0n * 32 + j * 64 + lane];
      }
      const floatx2* lB2 = (const floatx2*)&lds[buf][0][0][0];
      const floatx2* lE2 = (const floatx2*)&lds[buf][1][0][0];
      floatx2 pB[8], pE[8];
#pragma unroll
      for (int k = 0; k < 8; ++k) {  // slots descending: 31..24
        pB[k] = lB2[(31 - k) * 64 + lane];
        pE[k] = lE2[(31 - k) * 64 + lane];
      }
#pragma unroll
      for (int k = 0; k < CH; ++k) {
        const int s = c * CH + k;
        const floatx2 Bv = pB[k & 7];
        const floatx2 Ev = pE[k & 7];
        if (k + 8 < CH) {
          pB[k & 7] = lB2[(31 - (k + 8)) * 64 + lane];
          pE[k & 7] = lE2[(31 - (k + 8)) * 64 + lane];
        }
        const float tO = wave_shl1_zero(Ev.x * xE);  // lane l+1: Em*beta
        const float nxE = __builtin_fmaf(xE, Bv.x, Ev.y * xO);
        const float nxO = __builtin_fmaf(xO, Bv.y, tO);
        const bool cap = (s == smax);  // off-chain capture
        cE = cap ? nxE : cE;
        cO = cap ? nxO : cO;
        xE = nxE;
        xO = nxO;
      }
      if (c == ccap) capS = S;
      float m = readlane63(wave_max63(fmaxf(xE, xO)));
      if (m > 0.0f) {
        const float ex = floorf(__builtin_log2f(m));
        const float sc = __builtin_exp2f(-ex);
        xE *= sc;
        xO *= sc;
        S += ex;
      }
      floatx4* wB4 = (floatx4*)&lds[buf ^ 1][0][0][0];
      floatx4* wE4 = (floatx4*)&lds[buf ^ 1][1][0][0];
#pragma unroll
      for (int j = 0; j < 16; ++j) {
        wB4[j * 64 + lane] = rB[j];
        wE4[j * 64 + lane] = rE[j];
      }
    }
    float* sB = stateB + b * 132;
    ((floatx2*)sB)[lane] = floatx2{cE, cO};
    if (lane == 0) sB[128] = capS;
  }

  // ---- fused combine: second finisher per example does the dot + log ----
  __threadfence();  // release: state visible device-wide before flag bump
  int old = 0;
  if (lane == 0) old = atomicAdd(&flags[b], 1);
  old = __shfl(old, 0);
  if (old == 1) {
    __threadfence();  // acquire: other block's state now safe to read
    const float* sA = stateA + b * 132;
    const float* sB = stateB + b * 132;
    const floatx2 a = ((const floatx2*)sA)[lane];
    const floatx2 bb = ((const floatx2*)sB)[lane];
    float p = readlane63(wave_sum63(a.x * bb.x + a.y * bb.y));
    if (lane == 0) {
      out[b] = -((__builtin_log2f(p) + sA[128] + sB[128] -
                  9.0f * (float)(dtar + 1)) *
                 LN2);
    }
  }
}

extern "C" void kernel_launch(void* const* d_in, const int* in_sizes, int n_in,
                              void* d_out, int out_size, void* d_ws, size_t ws_size,
                              hipStream_t stream) {
  const float* acts = (const float*)d_in[0];
  const int* labels = (const int*)d_in[1];
  const int* act_lens = (const int*)d_in[2];
  const int* label_lens = (const int*)d_in[3];
  float* out = (float*)d_out;
  // ws layout: [flags 32 ints][blankD][emitD][stateA][stateB]
  int* flags = (int*)d_ws;
  float* blankD = (float*)d_ws + 32;                    // B*DALLOC*DSTR floats
  float* emitD = blankD + (size_t)B_ * DALLOC * DSTR;   // B*DALLOC*DSTR floats
  float* stateA = emitD + (size_t)B_ * DALLOC * DSTR;   // B*132 floats
  float* stateB = stateA + B_ * 132;                    // B*132 floats
  // Zero flags + staging arrays in one memset (flags MUST reset every call).
  hipMemsetAsync(d_ws, 0,
                 (32 + (size_t)2 * B_ * DALLOC * DSTR) * sizeof(float),
                 stream);
  const int nwaves2 = B_ * T_ * U_ / 2;
  lse_kernel<<<nwaves2 / 4, 256, 0, stream>>>(acts, labels, blankD, emitD);
  dp_kernel<<<16, 64, 0, stream>>>(blankD, emitD, act_lens, label_lens,
                                   stateA, stateB, flags, out);
}